// Round 1
// baseline (131.184 us; speedup 1.0000x reference)
//
#include <hip/hip_runtime.h>

#define TT 100
#define PP 1024
#define NN 65536
#define BIGV 1e30f

// One block per batch sample. 256 threads.
// Phase A: gather births/deaths, build per-dim masked (b,d) pairs in LDS,
//          count valid pairs per dim, find smallest valid index p1 (atomicMin).
// Phase B: find second-smallest valid index p2 (atomicMin over p > p1).
// Phase C: t-range from first <=2 valid pairs; linspace; per-t top-2 tent scan.
__global__ __launch_bounds__(256) void adpl_kernel(
    const float* __restrict__ inputs,     // [B, NN]
    const int*   __restrict__ dim_idx,    // [B, PP]
    const int*   __restrict__ birth_loc,  // [B, PP]
    const int*   __restrict__ death_loc,  // [B, PP]
    float*       __restrict__ out_land,   // [B, 2, TT, 2]
    float*       __restrict__ out_trange) // [B, 4]
{
    __shared__ float2 bd[2][PP];   // masked pairs per dim: invalid -> (BIG, -BIG)
    __shared__ int   s_count[2];
    __shared__ int   s_p1[2];
    __shared__ int   s_p2[2];
    __shared__ float s_tmin[2], s_tmax[2];
    __shared__ int   s_maxland[2]; // float bits, values >= 0 so int-monotone

    const int b   = blockIdx.x;
    const int tid = threadIdx.x;

    if (tid < 2) {
        s_count[tid]   = 0;
        s_p1[tid]      = PP;
        s_p2[tid]      = PP;
        s_maxland[tid] = 0; // == __float_as_int(0.0f)
    }
    __syncthreads();

    // ---- Phase A ----
    int c0 = 0, c1 = 0;
    int lmin0 = PP, lmin1 = PP;
    for (int p = tid; p < PP; p += 256) {
        const int di = dim_idx[(size_t)b * PP + p];
        const int bl = birth_loc[(size_t)b * PP + p];
        const int dl = death_loc[(size_t)b * PP + p];
        const float bv = inputs[(size_t)b * NN + bl];
        const float dv = inputs[(size_t)b * NN + dl];
        const bool v0 = (di == 0);
        bd[0][p] = v0 ? make_float2(bv, dv) : make_float2(BIGV, -BIGV);
        bd[1][p] = v0 ? make_float2(BIGV, -BIGV) : make_float2(bv, dv);
        if (v0) { c0++; lmin0 = min(lmin0, p); }
        else    { c1++; lmin1 = min(lmin1, p); }
    }
    if (c0) { atomicAdd(&s_count[0], c0); atomicMin(&s_p1[0], lmin0); }
    if (c1) { atomicAdd(&s_count[1], c1); atomicMin(&s_p1[1], lmin1); }
    __syncthreads();

    // ---- Phase B: second-smallest valid index per dim ----
    const int p1_0 = s_p1[0], p1_1 = s_p1[1];
    for (int p = tid; p < PP; p += 256) {
        const float x0 = bd[0][p].x;
        const float x1 = bd[1][p].x;
        if (x0 < BIGV && p > p1_0) atomicMin(&s_p2[0], p);
        if (x1 < BIGV && p > p1_1) atomicMin(&s_p2[1], p);
    }
    __syncthreads();

    // ---- t-range from first min(count,2) valid pairs ----
    if (tid < 2) {
        const int d   = tid;
        const int cnt = s_count[d];
        float tmin = 0.f, tmax = 0.f;
        if (cnt > 0) {
            const float2 e1 = bd[d][s_p1[d]];
            tmin = e1.x; tmax = e1.y;
            if (cnt > 1) {
                const float2 e2 = bd[d][s_p2[d]];
                tmin = fminf(tmin, e2.x);
                tmax = fmaxf(tmax, e2.y);
            }
        }
        s_tmin[d] = tmin;
        s_tmax[d] = tmax;
    }
    __syncthreads();

    // ---- Phase C: per-t top-2 over all pairs ----
    const int d = tid >> 7;     // wave-uniform dim
    const int t = tid & 127;
    if (t < TT) {
        const float tmin = s_tmin[d], tmax = s_tmax[d];
        const float step = (tmax - tmin) * (1.0f / (TT - 1));
        const float tv = (t == TT - 1) ? tmax : fmaf((float)t, step, tmin);
        float m1 = 0.f, m2 = 0.f;   // implicit clamp-at-0 baseline
        const float2* __restrict__ arr = bd[d];
        #pragma unroll 8
        for (int p = 0; p < PP; p++) {
            const float2 e = arr[p];
            const float f = fminf(tv - e.x, e.y - tv); // invalid -> very negative
            m2 = fmaxf(m2, fminf(m1, f));
            m1 = fmaxf(m1, f);
        }
        const size_t base = ((size_t)(b * 2 + d) * TT + t) * 2;
        out_land[base + 0] = m1;
        out_land[base + 1] = m2;
        atomicMax(&s_maxland[d], __float_as_int(m1));
    }
    __syncthreads();

    if (tid < 2) {
        const int d = tid;
        const bool nz = (s_count[d] > 0) && (__int_as_float(s_maxland[d]) > 0.f);
        out_trange[(size_t)b * 4 + 2 * d + 0] = nz ? s_tmin[d] : 0.f;
        out_trange[(size_t)b * 4 + 2 * d + 1] = nz ? s_tmax[d] : 0.f;
    }
}

extern "C" void kernel_launch(void* const* d_in, const int* in_sizes, int n_in,
                              void* d_out, int out_size, void* d_ws, size_t ws_size,
                              hipStream_t stream) {
    const float* inputs    = (const float*)d_in[0];
    const int*   dim_idx   = (const int*)d_in[1];
    const int*   birth_loc = (const int*)d_in[2];
    const int*   death_loc = (const int*)d_in[3];

    const int B = in_sizes[1] / PP;   // 256

    float* out_land   = (float*)d_out;
    float* out_trange = out_land + (size_t)B * 2 * TT * 2;

    adpl_kernel<<<B, 256, 0, stream>>>(inputs, dim_idx, birth_loc, death_loc,
                                       out_land, out_trange);
}

// Round 2
// 106.738 us; speedup vs baseline: 1.2290x; 1.2290x over previous
//
#include <hip/hip_runtime.h>

#define TT 100
#define PP 1024
#define NN 65536
#define BIGV 1e30f

// One block per batch sample. 1024 threads (16 waves -> 4 waves/SIMD).
// Phase A: 1 pair/thread gather; per-wave ballot masks give count + first two
//          valid indices per dim (no atomics, no second pass).
// Phase C: per-(d,t,chunk) partial top-2 over 256 interleaved pairs, LDS merge.
__global__ __launch_bounds__(1024) void adpl_kernel(
    const float* __restrict__ inputs,     // [B, NN]
    const int*   __restrict__ dim_idx,    // [B, PP]
    const int*   __restrict__ birth_loc,  // [B, PP]
    const int*   __restrict__ death_loc,  // [B, PP]
    float*       __restrict__ out_land,   // [B, 2, TT, 2]
    float*       __restrict__ out_trange) // [B, 4]
{
    __shared__ float2 bd[2][PP];                 // masked pairs; invalid -> (BIG,-BIG)
    __shared__ unsigned long long s_mask[16];    // per-wave valid-mask for dim 0
    __shared__ float  s_tmin[2], s_tmax[2];
    __shared__ int    s_count[2];
    __shared__ int    s_maxland[2];              // float bits; values >= 0 so int-monotone
    __shared__ float2 s_part[2][TT][4];          // partial (m1,m2) per (d,t,chunk)

    const int b   = blockIdx.x;
    const int tid = threadIdx.x;

    if (tid < 2) s_maxland[tid] = 0;             // == __float_as_int(0.0f)

    // ---- Phase A: one pair per thread ----
    {
        const int p  = tid;
        const int di = dim_idx [(size_t)b * PP + p];
        const int bl = birth_loc[(size_t)b * PP + p];
        const int dl = death_loc[(size_t)b * PP + p];
        const float bv = inputs[(size_t)b * NN + bl];
        const float dv = inputs[(size_t)b * NN + dl];
        const bool v0 = (di == 0);
        bd[0][p] = v0 ? make_float2(bv, dv) : make_float2(BIGV, -BIGV);
        bd[1][p] = v0 ? make_float2(BIGV, -BIGV) : make_float2(bv, dv);
        const unsigned long long m0 = __ballot(v0);
        if ((tid & 63) == 0) s_mask[tid >> 6] = m0;
    }
    __syncthreads();

    // ---- t-range: count + first two valid indices per dim, from ballot masks ----
    if (tid < 2) {
        const int d = tid;
        int cnt = 0, p1 = -1, p2 = -1;
        for (int w = 0; w < 16; w++) {
            unsigned long long m = (d == 0) ? s_mask[w] : ~s_mask[w];
            cnt += __popcll(m);
            if (p2 < 0 && m) {
                if (p1 < 0) {
                    p1 = w * 64 + __ffsll(m) - 1;
                    m &= m - 1;
                    if (m) p2 = w * 64 + __ffsll(m) - 1;
                } else {
                    p2 = w * 64 + __ffsll(m) - 1;
                }
            }
        }
        float tmin = 0.f, tmax = 0.f;
        if (cnt > 0) {
            const float2 e1 = bd[d][p1];
            tmin = e1.x; tmax = e1.y;
            if (cnt > 1) {
                const float2 e2 = bd[d][p2];
                tmin = fminf(tmin, e2.x);
                tmax = fmaxf(tmax, e2.y);
            }
        }
        s_tmin[d] = tmin; s_tmax[d] = tmax; s_count[d] = cnt;
    }
    __syncthreads();

    // ---- Phase C: partial top-2 per (d, t, chunk) ----
    {
        const int d   = tid >> 9;        // wave-uniform dim (8 waves each)
        const int idx = tid & 511;
        const int t   = idx >> 2;        // 0..127
        const int c   = idx & 3;         // chunk 0..3
        if (t < TT) {
            const float tmin = s_tmin[d], tmax = s_tmax[d];
            const float step = (tmax - tmin) * (1.0f / (TT - 1));
            const float tv = (t == TT - 1) ? tmax : fmaf((float)t, step, tmin);
            float M1 = 0.f, M2 = 0.f;    // implicit clamp-at-0 baseline
            const float2* __restrict__ arr = bd[d];
            #pragma unroll 8
            for (int i = 0; i < 256; i++) {
                const float2 e = arr[4 * i + c];          // lane quad -> 4 distinct banks
                const float f = fminf(tv - e.x, e.y - tv); // invalid -> very negative
                M2 = fmaxf(M2, fminf(M1, f));
                M1 = fmaxf(M1, f);
            }
            s_part[d][t][c] = make_float2(M1, M2);
        }
    }
    __syncthreads();

    // ---- merge 4 partials per (d,t), write landscape ----
    if (tid < 256) {
        const int d2 = tid >> 7, t2 = tid & 127;
        if (t2 < TT) {
            float m1 = 0.f, m2 = 0.f;
            #pragma unroll
            for (int cc = 0; cc < 4; cc++) {
                const float2 pr = s_part[d2][t2][cc];
                m2 = fmaxf(m2, fminf(m1, pr.x));
                m1 = fmaxf(m1, pr.x);
                m2 = fmaxf(m2, pr.y);   // pr.y <= pr.x <= m1 here
            }
            const size_t base = ((size_t)(b * 2 + d2) * TT + t2) * 2;
            out_land[base + 0] = m1;
            out_land[base + 1] = m2;
            atomicMax(&s_maxland[d2], __float_as_int(m1));
        }
    }
    __syncthreads();

    if (tid < 2) {
        const int d = tid;
        const bool nz = (s_count[d] > 0) && (__int_as_float(s_maxland[d]) > 0.f);
        out_trange[(size_t)b * 4 + 2 * d + 0] = nz ? s_tmin[d] : 0.f;
        out_trange[(size_t)b * 4 + 2 * d + 1] = nz ? s_tmax[d] : 0.f;
    }
}

extern "C" void kernel_launch(void* const* d_in, const int* in_sizes, int n_in,
                              void* d_out, int out_size, void* d_ws, size_t ws_size,
                              hipStream_t stream) {
    const float* inputs    = (const float*)d_in[0];
    const int*   dim_idx   = (const int*)d_in[1];
    const int*   birth_loc = (const int*)d_in[2];
    const int*   death_loc = (const int*)d_in[3];

    const int B = in_sizes[1] / PP;   // 256

    float* out_land   = (float*)d_out;
    float* out_trange = out_land + (size_t)B * 2 * TT * 2;

    adpl_kernel<<<B, 1024, 0, stream>>>(inputs, dim_idx, birth_loc, death_loc,
                                        out_land, out_trange);
}

// Round 3
// 105.401 us; speedup vs baseline: 1.2446x; 1.0127x over previous
//
#include <hip/hip_runtime.h>

#define TT 100
#define PP 1024
#define NN 65536
#define BIGV 1e30f

// One block per (batch sample, homology dim). Grid (B, 2), 1024 threads
// (16 waves). 2 blocks/CU -> 32 waves/CU full occupancy.
// Phase A: 1 pair/thread gather; mask by (dim_idx == d); ballot masks give
//          count + first two valid indices (t-range) with no atomics.
// Phase C: per-(t,chunk) partial top-2 over 128 interleaved pairs (8 chunks),
//          padded-LDS merge.
__global__ __launch_bounds__(1024, 8) void adpl_kernel(
    const float* __restrict__ inputs,     // [B, NN]
    const int*   __restrict__ dim_idx,    // [B, PP]
    const int*   __restrict__ birth_loc,  // [B, PP]
    const int*   __restrict__ death_loc,  // [B, PP]
    float*       __restrict__ out_land,   // [B, 2, TT, 2]
    float*       __restrict__ out_trange) // [B, 4]
{
    __shared__ float2 bd[PP];                    // masked pairs; invalid -> (BIG,-BIG)
    __shared__ unsigned long long s_mask[16];    // per-wave valid mask
    __shared__ float  s_tmin, s_tmax;
    __shared__ int    s_count;
    __shared__ int    s_maxland;                 // float bits; values >= 0 so int-monotone
    __shared__ float2 s_part[TT][9];             // partial (m1,m2) per (t,chunk); pad 8->9

    const int b   = blockIdx.x;
    const int d   = blockIdx.y;
    const int tid = threadIdx.x;

    if (tid == 0) s_maxland = 0;                 // == __float_as_int(0.0f)

    // ---- Phase A: one pair per thread ----
    {
        const int p  = tid;
        const int di = dim_idx [(size_t)b * PP + p];
        const int bl = birth_loc[(size_t)b * PP + p];
        const int dl = death_loc[(size_t)b * PP + p];
        const float bv = inputs[(size_t)b * NN + bl];
        const float dv = inputs[(size_t)b * NN + dl];
        const bool v = (di == d);
        bd[p] = v ? make_float2(bv, dv) : make_float2(BIGV, -BIGV);
        const unsigned long long m = __ballot(v);
        if ((tid & 63) == 0) s_mask[tid >> 6] = m;
    }
    __syncthreads();

    // ---- t-range: count + first two valid indices, from ballot masks ----
    if (tid == 0) {
        int cnt = 0, p1 = -1, p2 = -1;
        for (int w = 0; w < 16; w++) {
            unsigned long long m = s_mask[w];
            cnt += __popcll(m);
            if (p2 < 0 && m) {
                if (p1 < 0) {
                    p1 = w * 64 + __ffsll(m) - 1;
                    m &= m - 1;
                    if (m) p2 = w * 64 + __ffsll(m) - 1;
                } else {
                    p2 = w * 64 + __ffsll(m) - 1;
                }
            }
        }
        float tmin = 0.f, tmax = 0.f;
        if (cnt > 0) {
            const float2 e1 = bd[p1];
            tmin = e1.x; tmax = e1.y;
            if (cnt > 1) {
                const float2 e2 = bd[p2];
                tmin = fminf(tmin, e2.x);
                tmax = fmaxf(tmax, e2.y);
            }
        }
        s_tmin = tmin; s_tmax = tmax; s_count = cnt;
    }
    __syncthreads();

    // ---- Phase C: partial top-2 per (t, chunk); 8 chunks x 128 pairs ----
    {
        const int t = tid >> 3;          // 0..127
        const int c = tid & 7;           // chunk 0..7
        if (t < TT) {
            const float tmin = s_tmin, tmax = s_tmax;
            const float step = (tmax - tmin) * (1.0f / (TT - 1));
            const float tv = (t == TT - 1) ? tmax : fmaf((float)t, step, tmin);
            float M1 = 0.f, M2 = 0.f;    // implicit clamp-at-0 baseline
            #pragma unroll 8
            for (int i = 0; i < 128; i++) {
                const float2 e = bd[8 * i + c];            // broadcast across t-groups
                const float f = fminf(tv - e.x, e.y - tv); // invalid -> very negative
                M2 = fmaxf(M2, fminf(M1, f));
                M1 = fmaxf(M1, f);
            }
            s_part[t][c] = make_float2(M1, M2);
        }
    }
    __syncthreads();

    // ---- merge 8 partials per t, write landscape ----
    if (tid < TT) {
        const int t = tid;
        float m1 = 0.f, m2 = 0.f;
        #pragma unroll
        for (int cc = 0; cc < 8; cc++) {
            const float2 pr = s_part[t][cc];
            m2 = fmaxf(m2, fminf(m1, pr.x));
            m1 = fmaxf(m1, pr.x);
            m2 = fmaxf(m2, pr.y);        // pr.y <= pr.x, so top-2 merge is exact
        }
        const size_t base = ((size_t)(b * 2 + d) * TT + t) * 2;
        out_land[base + 0] = m1;
        out_land[base + 1] = m2;
        atomicMax(&s_maxland, __float_as_int(m1));
    }
    __syncthreads();

    if (tid == 0) {
        const bool nz = (s_count > 0) && (__int_as_float(s_maxland) > 0.f);
        out_trange[(size_t)b * 4 + 2 * d + 0] = nz ? s_tmin : 0.f;
        out_trange[(size_t)b * 4 + 2 * d + 1] = nz ? s_tmax : 0.f;
    }
}

extern "C" void kernel_launch(void* const* d_in, const int* in_sizes, int n_in,
                              void* d_out, int out_size, void* d_ws, size_t ws_size,
                              hipStream_t stream) {
    const float* inputs    = (const float*)d_in[0];
    const int*   dim_idx   = (const int*)d_in[1];
    const int*   birth_loc = (const int*)d_in[2];
    const int*   death_loc = (const int*)d_in[3];

    const int B = in_sizes[1] / PP;   // 256

    float* out_land   = (float*)d_out;
    float* out_trange = out_land + (size_t)B * 2 * TT * 2;

    dim3 grid(B, 2);
    adpl_kernel<<<grid, 1024, 0, stream>>>(inputs, dim_idx, birth_loc, death_loc,
                                           out_land, out_trange);
}